// Round 8
// baseline (155.435 us; speedup 1.0000x reference)
//
#include <hip/hip_runtime.h>
#include <cmath>

// RestorationLoss = (1 - mean(SSIM(r_low, r_high))) + mean((r_low - r_high)^2)
// Separable 11x11 gaussian; 4 conv fields: mu1, mu2, S=conv(a^2+b^2), P=conv(ab).
// out = 1 + sum(d^2 - ssim_px)/N.
// R19 = R18 + depth-2 cross-tile prefetch (exposed-latency round).
// R18 post-mortem: offered ~170 VGPR cap, allocator stayed at 64 -> headroom
// does nothing unless values are FORCED live. Post-barrier staging waited
// ~600-1500 cy/tile on B+C batches with only ~300 cy conv cover, and the 3
// identical persistent blocks/CU stall in lockstep (correlated waits).
//  - xB batch (tile t+1 rows +27..+58) now loads BEFORE phase-2 of tile t,
//    alongside xP (A batch): both in flight under phase-2's ~2000 cy.
//  - post-barrier: convA -> issue C (reuse xP) -> convB -> convC; only C's
//    ~600 cy remains exposed.
//  - VGPR must rise to ~110-140 (forced live); launch_bounds(256,3) allows
//    ~170 at 3 waves/SIMD. Spill tripwire: WRITE_SIZE stays ~24 KB.
// Frozen: persistent 32-col strips (768 blocks = 3/CU), NT=8 chained tiles,
// fp32 float4 hbuf[74][33] (39 KB), packed-f32 (v2f) conv math, MSE folded
// into phase-1 (rl in [5,69)), interior-col fast path, rcp ssim epilogue,
// 256 thr, unroll-1 tile loop.

#define HH 512
#define WW 512
#define TILE_H 64
#define TILE_W 32
#define NT (HH / TILE_H)                          // 8 chained tiles per block
#define HB (TILE_H + 10)                          // 74 staged rows
#define LDW 33                                    // padded row: 33 float4s
#define NPLANES 48
#define CT (WW / TILE_W)                          // 16
#define NBLOCKS (NPLANES * CT)                    // 768 = 3 per CU exactly

struct GW { float g[11]; };

typedef float v2f __attribute__((ext_vector_type(2)));

__global__ __launch_bounds__(256, 3)
void ssim_main(const float* __restrict__ img1, const float* __restrict__ img2,
               float* __restrict__ partial, GW gw)
{
    __shared__ float4 hbuf[HB][LDW];              // (mu1,mu2,S,P) fp32: 39072 B
    __shared__ float red[4];

    const int tid   = threadIdx.x;
    const int bx    = blockIdx.x;                 // column strip
    const int plane = blockIdx.y;
    const int col0  = bx * TILE_W;
    const float* p1 = img1 + (size_t)plane * (HH * WW);
    const float* p2 = img2 + (size_t)plane * (HH * WW);

    const int cg    = tid & 7;                    // col group: tile cols 4cg..4cg+3
    const int rs    = tid >> 3;                   // 0..31 row slot
    const int cbase = col0 + 4 * cg - 8;          // 20-float window, 16B aligned
    const bool interiorCol = (bx > 0) && (bx < CT - 1);  // all 5 vectors in-bounds

    float local = 0.f;                            // mse (phase 1) - ssim (phase 2)

    // 5 float4-pair loads; fast path for interior columns + in-bounds row.
    // OOB vectors (col OR row) become zeros == reference zero padding.
    auto loadRow = [&](int grow, float4* x1, float4* x2) {
        const bool rowOK = (grow >= 0) && (grow < HH);
        const int growc = min(max(grow, 0), HH - 1);      // addr always in-bounds
        const float* r1 = p1 + (size_t)growc * WW;
        const float* r2 = p2 + (size_t)growc * WW;
        if (rowOK && interiorCol) {
            #pragma unroll
            for (int v = 0; v < 5; ++v) {
                x1[v] = *reinterpret_cast<const float4*>(r1 + cbase + 4 * v);
                x2[v] = *reinterpret_cast<const float4*>(r2 + cbase + 4 * v);
            }
        } else {
            #pragma unroll
            for (int v = 0; v < 5; ++v) {
                const int c0 = cbase + 4 * v;
                if (rowOK && c0 >= 0 && c0 + 4 <= WW) {
                    x1[v] = *reinterpret_cast<const float4*>(r1 + c0);
                    x2[v] = *reinterpret_cast<const float4*>(r2 + c0);
                } else {
                    x1[v] = make_float4(0.f, 0.f, 0.f, 0.f);
                    x2[v] = make_float4(0.f, 0.f, 0.f, 0.f);
                }
            }
        }
    };

    // horizontal conv of one staged row -> fp32 hbuf[rl][col]
    // + MSE for tile rows (rl in [5,68]); staging-overlap rows excluded.
    auto convStore = [&](int rl, const float4* x1v, const float4* x2v) {
        const float* x1 = reinterpret_cast<const float*>(x1v);
        const float* x2 = reinterpret_cast<const float*>(x2v);
        if (rl >= 5 && rl < 69) {                 // this thread's 4 tile pixels
            #pragma unroll
            for (int i = 0; i < 4; ++i) {
                float d = x1[8 + i] - x2[8 + i];
                local += d * d;
            }
        }
        v2f acc01[4], acc23[4];
        #pragma unroll
        for (int i = 0; i < 4; ++i) {
            acc01[i] = (v2f){0.f, 0.f};
            acc23[i] = (v2f){0.f, 0.f};
        }
        #pragma unroll
        for (int e = 3; e <= 16; ++e) {           // out col i uses e = i+j+3
            float a  = x1[e], b = x2[e];
            v2f ab = (v2f){a, b};
            v2f t  = ab * ab;                     // pk_mul: (a^2, b^2)
            v2f vv = (v2f){t.x + t.y, a * b};     // (S-term, P-term)
            #pragma unroll
            for (int i = 0; i < 4; ++i) {
                int j = e - 3 - i;
                if (j >= 0 && j < 11) {
                    float w = gw.g[j];
                    v2f wv = (v2f){w, w};
                    acc01[i] += wv * ab;          // pk_fma
                    acc23[i] += wv * vv;          // pk_fma
                }
            }
        }
        #pragma unroll
        for (int i = 0; i < 4; ++i)
            hbuf[rl][4 * cg + i] = make_float4(acc01[i].x, acc01[i].y,
                                               acc23[i].x, acc23[i].y);
    };

    const bool third = (rs < 10);

    // ---- initial full staging of tile 0 (R9 pipeline) ----
    {
        float4 xA1[5], xA2[5], xB1[5], xB2[5];
        loadRow(-5 + rs, xA1, xA2);               // rows -5..26 (top zero-fill)
        loadRow(27 + rs, xB1, xB2);               // rows 27..58
        convStore(rs, xA1, xA2);                  // under B's load latency
        if (third) loadRow(59 + rs, xA1, xA2);    // rows 59..68
        convStore(rs + 32, xB1, xB2);
        if (third) convStore(rs + 64, xA1, xA2);
    }

    float4 xP1[5], xP2[5];                        // next-tile batch-A prefetch
    float4 xB1[5], xB2[5];                        // next-tile batch-B prefetch
    #pragma unroll 1
    for (int t = 0; t < NT; ++t) {
        const int row0 = t * TILE_H;
        __syncthreads();                          // staging of tile t complete

        if (t + 1 < NT) {                         // depth-2 prefetch of tile t+1:
            loadRow(row0 + TILE_H - 5 + rs, xP1, xP2);   // batch A (rows -5..26)
            loadRow(row0 + TILE_H + 27 + rs, xB1, xB2);  // batch B (rows 27..58)
        }

        // ---- Phase 2: vertical conv (18 b128 reads / 8 rows) + ssim ----
        {
            const int tx = tid & 31;              // pixel column
            const int rg = tid >> 5;              // 0..7 -> rows 8rg..8rg+7
            v2f res01[8], res23[8];
            #pragma unroll
            for (int p = 0; p < 8; ++p) {
                res01[p] = (v2f){0.f, 0.f};
                res23[p] = (v2f){0.f, 0.f};
            }
            #pragma unroll
            for (int j = 0; j < 18; ++j) {        // window rows rg*8 .. rg*8+17
                float4 u = hbuf[rg * 8 + j][tx];
                v2f f01 = (v2f){u.x, u.y};        // (mu1, mu2)
                v2f f23 = (v2f){u.z, u.w};        // (S, P)
                #pragma unroll
                for (int p = 0; p < 8; ++p) {
                    int tt = j - p;
                    if (tt >= 0 && tt < 11) {
                        float w = gw.g[tt];
                        v2f wv = (v2f){w, w};
                        res01[p] += wv * f01;     // pk_fma
                        res23[p] += wv * f23;     // pk_fma
                    }
                }
            }
            const float C1c = 0.0001f, C2c = 0.0009f;
            #pragma unroll
            for (int p = 0; p < 8; ++p) {
                float mu1 = res01[p].x, mu2 = res01[p].y;
                float S   = res23[p].x, P   = res23[p].y;
                float m11 = mu1 * mu1, m22 = mu2 * mu2, m12 = mu1 * mu2;
                float num = (2.f * m12 + C1c) * (2.f * (P - m12) + C2c);
                float den = (m11 + m22 + C1c) * ((S - m11 - m22) + C2c);
                float inv = __builtin_amdgcn_rcpf(den);  // ~1ulp vs 2.3e-2 thr
                local -= num * inv;
            }
        }

        if (t + 1 < NT) {
            __syncthreads();                      // phase-2 reads done; reuse hbuf
            const int nrow0 = row0 + TILE_H;
            convStore(rs, xP1, xP2);              // A (prefetched, long complete)
            if (third) loadRow(nrow0 + 59 + rs, xP1, xP2);   // issue C into xP
            convStore(rs + 32, xB1, xB2);         // B (prefetched) covers C
            if (third) convStore(rs + 64, xP1, xP2);         // C
        }
    }

    // ---- block reduce ----
    #pragma unroll
    for (int off = 32; off > 0; off >>= 1) local += __shfl_down(local, off);
    if ((tid & 63) == 0) red[tid >> 6] = local;
    __syncthreads();
    if (tid == 0)
        partial[plane * CT + bx] = (red[0] + red[1]) + (red[2] + red[3]);
}

__global__ __launch_bounds__(256)
void ssim_finish(const float* __restrict__ partial, float* __restrict__ out)
{
    __shared__ float red[256];
    float s = 0.f;
    #pragma unroll
    for (int i = 0; i < NBLOCKS / 256; ++i)       // 3 independent loads
        s += partial[i * 256 + threadIdx.x];
    red[threadIdx.x] = s;
    __syncthreads();
    for (int step = 128; step > 0; step >>= 1) {
        if ((int)threadIdx.x < step) red[threadIdx.x] += red[threadIdx.x + step];
        __syncthreads();
    }
    if (threadIdx.x == 0)
        out[0] = 1.0f + red[0] * (1.0f / 12582912.0f);
}

extern "C" void kernel_launch(void* const* d_in, const int* in_sizes, int n_in,
                              void* d_out, int out_size, void* d_ws, size_t ws_size,
                              hipStream_t stream)
{
    const float* r_low  = (const float*)d_in[0];
    const float* r_high = (const float*)d_in[1];
    float* out     = (float*)d_out;
    float* partial = (float*)d_ws;                       // 768 floats

    GW gw;                                               // gaussian -> SGPRs
    {
        float s = 0.f;
        for (int i = 0; i < 11; ++i) {
            float c = (float)(i - 5);
            gw.g[i] = expf(-(c * c) / 4.5f);             // 2*sigma^2 = 4.5
            s += gw.g[i];
        }
        for (int i = 0; i < 11; ++i) gw.g[i] /= s;
    }

    dim3 grid(CT, NPLANES);
    ssim_main<<<grid, dim3(256), 0, stream>>>(r_low, r_high, partial, gw);
    ssim_finish<<<1, dim3(256), 0, stream>>>(partial, out);
}

// Round 9
// 150.583 us; speedup vs baseline: 1.0322x; 1.0322x over previous
//
#include <hip/hip_runtime.h>
#include <hip/hip_fp16.h>
#include <cmath>

// RestorationLoss = (1 - mean(SSIM(r_low, r_high))) + mean((r_low - r_high)^2)
// Separable 11x11 gaussian; 4 conv fields: mu1, mu2, S=conv(a^2+b^2), P=conv(ab).
// out = 1 + sum(d^2 - ssim_px)/N.
// R20 = R17 skeleton at 6 blocks/CU (residency round).
// R19 post-mortem: depth-2 prefetch regressed (reverted; R18=65.5us best).
// Across R11-R16 the ~12-wave/CU "pin" was measured only under block CHURN;
// R17+ froze residency at 3 blocks/CU by construction. Never tested >12
// resident waves -- and the profile (VALU 47%, LDS ~44%, HBM 27%, per-wave
// issue ~16%) says latency-starved, not pipe-bound. Test it:
//  - grid 16 cols x 48 planes x 2 vertical halves = 1536 persistent blocks
//    = 6/CU exact; NT=4 chained 64-row tiles per block.
//  - fp16-packed hbuf (19.5 KB) so 6 x LDS fits in 160 KB; also halves
//    phase-2 LDS traffic (b64 reads) now that 6 blocks share the pipe.
//    Measured cvt cost only ~2.2us (R17 vs R18).
//  - launch_bounds(256,4): empirical VGPR cap 64; R17 hit exactly 64 with
//    this identical pipeline. Spill tripwire: WRITE_SIZE stays ~25 KB.
//  - depth-1 cross-tile prefetch (xP batch A only) = R17's proven shape.
// Falsifier: OccupancyPercent stuck at ~26% => 12-wave pin is HW/dispatch,
// not churn; next lever = shorten dependency chains (MFMA vertical conv).

#define HH 512
#define WW 512
#define TILE_H 64
#define TILE_W 32
#define NT 4                                      // tiles per block (half strip)
#define HB (TILE_H + 10)                          // 74 staged rows
#define LDW 33                                    // padded row: 33 uint2
#define NPLANES 48
#define CT (WW / TILE_W)                          // 16
#define NBLOCKS (NPLANES * CT * 2)                // 1536 = 6 per CU exactly

struct GW { float g[11]; };

typedef float v2f __attribute__((ext_vector_type(2)));

__device__ __forceinline__ unsigned pack2(float a, float b) {
    __half2 h = __floats2half2_rn(a, b);
    return __builtin_bit_cast(unsigned, h);
}
__device__ __forceinline__ v2f unpack2(unsigned u) {
    __half2 h = __builtin_bit_cast(__half2, u);
    float2 f = __half22float2(h);
    return (v2f){f.x, f.y};
}

__global__ __launch_bounds__(256, 4)
void ssim_main(const float* __restrict__ img1, const float* __restrict__ img2,
               float* __restrict__ partial, GW gw)
{
    __shared__ uint2 hbuf[HB][LDW];               // (mu1,mu2)|(S,P) fp16: 19536 B
    __shared__ float red[4];

    const int tid   = threadIdx.x;
    const int bx    = blockIdx.x;                 // column strip
    const int half  = blockIdx.y;                 // vertical half: rows 256*half..
    const int plane = blockIdx.z;
    const int base  = half * (NT * TILE_H);       // 0 or 256
    const int col0  = bx * TILE_W;
    const float* p1 = img1 + (size_t)plane * (HH * WW);
    const float* p2 = img2 + (size_t)plane * (HH * WW);

    const int cg    = tid & 7;                    // col group: tile cols 4cg..4cg+3
    const int rs    = tid >> 3;                   // 0..31 row slot
    const int cbase = col0 + 4 * cg - 8;          // 20-float window, 16B aligned
    const bool interiorCol = (bx > 0) && (bx < CT - 1);  // all 5 vectors in-bounds

    float local = 0.f;                            // mse (phase 1) - ssim (phase 2)

    // 5 float4-pair loads; fast path for interior columns + in-bounds row.
    // OOB vectors (col OR row) become zeros == reference zero padding.
    auto loadRow = [&](int grow, float4* x1, float4* x2) {
        const bool rowOK = (grow >= 0) && (grow < HH);
        const int growc = min(max(grow, 0), HH - 1);      // addr always in-bounds
        const float* r1 = p1 + (size_t)growc * WW;
        const float* r2 = p2 + (size_t)growc * WW;
        if (rowOK && interiorCol) {
            #pragma unroll
            for (int v = 0; v < 5; ++v) {
                x1[v] = *reinterpret_cast<const float4*>(r1 + cbase + 4 * v);
                x2[v] = *reinterpret_cast<const float4*>(r2 + cbase + 4 * v);
            }
        } else {
            #pragma unroll
            for (int v = 0; v < 5; ++v) {
                const int c0 = cbase + 4 * v;
                if (rowOK && c0 >= 0 && c0 + 4 <= WW) {
                    x1[v] = *reinterpret_cast<const float4*>(r1 + c0);
                    x2[v] = *reinterpret_cast<const float4*>(r2 + c0);
                } else {
                    x1[v] = make_float4(0.f, 0.f, 0.f, 0.f);
                    x2[v] = make_float4(0.f, 0.f, 0.f, 0.f);
                }
            }
        }
    };

    // horizontal conv of one staged row -> packed fp16 hbuf[rl][col]
    // + MSE for tile rows (rl in [5,68]); staging-overlap rows excluded so
    // each global row is counted exactly once across chained tiles/halves.
    auto convStore = [&](int rl, const float4* x1v, const float4* x2v) {
        const float* x1 = reinterpret_cast<const float*>(x1v);
        const float* x2 = reinterpret_cast<const float*>(x2v);
        if (rl >= 5 && rl < 69) {                 // this thread's 4 tile pixels
            #pragma unroll
            for (int i = 0; i < 4; ++i) {
                float d = x1[8 + i] - x2[8 + i];
                local += d * d;
            }
        }
        v2f acc01[4], acc23[4];
        #pragma unroll
        for (int i = 0; i < 4; ++i) {
            acc01[i] = (v2f){0.f, 0.f};
            acc23[i] = (v2f){0.f, 0.f};
        }
        #pragma unroll
        for (int e = 3; e <= 16; ++e) {           // out col i uses e = i+j+3
            float a  = x1[e], b = x2[e];
            v2f ab = (v2f){a, b};
            v2f t  = ab * ab;                     // pk_mul: (a^2, b^2)
            v2f vv = (v2f){t.x + t.y, a * b};     // (S-term, P-term)
            #pragma unroll
            for (int i = 0; i < 4; ++i) {
                int j = e - 3 - i;
                if (j >= 0 && j < 11) {
                    float w = gw.g[j];
                    v2f wv = (v2f){w, w};
                    acc01[i] += wv * ab;          // pk_fma
                    acc23[i] += wv * vv;          // pk_fma
                }
            }
        }
        #pragma unroll
        for (int i = 0; i < 4; ++i) {
            uint2 px;
            px.x = pack2(acc01[i].x, acc01[i].y);
            px.y = pack2(acc23[i].x, acc23[i].y);
            hbuf[rl][4 * cg + i] = px;            // adjacent b64 stores
        }
    };

    const bool third = (rs < 10);

    // ---- initial full staging of tile 0 (R9 pipeline) ----
    {
        float4 xA1[5], xA2[5], xB1[5], xB2[5];
        loadRow(base - 5 + rs, xA1, xA2);         // rows -5..26 (zero-fill OOB)
        loadRow(base + 27 + rs, xB1, xB2);        // rows 27..58
        convStore(rs, xA1, xA2);                  // under B's load latency
        if (third) loadRow(base + 59 + rs, xA1, xA2);    // rows 59..68
        convStore(rs + 32, xB1, xB2);
        if (third) convStore(rs + 64, xA1, xA2);
    }

    float4 xP1[5], xP2[5];                        // next-tile batch-A prefetch
    #pragma unroll 1
    for (int t = 0; t < NT; ++t) {
        const int row0 = base + t * TILE_H;
        __syncthreads();                          // staging of tile t complete

        if (t + 1 < NT)                           // T14: issue next tile's A loads
            loadRow(row0 + TILE_H - 5 + rs, xP1, xP2);

        // ---- Phase 2: vertical conv (18 b64 reads / 8 rows) + ssim ----
        {
            const int tx = tid & 31;              // pixel column
            const int rg = tid >> 5;              // 0..7 -> rows 8rg..8rg+7
            v2f res01[8], res23[8];
            #pragma unroll
            for (int p = 0; p < 8; ++p) {
                res01[p] = (v2f){0.f, 0.f};
                res23[p] = (v2f){0.f, 0.f};
            }
            #pragma unroll
            for (int j = 0; j < 18; ++j) {        // window rows rg*8 .. rg*8+17
                uint2 u = hbuf[rg * 8 + j][tx];
                v2f f01 = unpack2(u.x);           // (mu1, mu2)
                v2f f23 = unpack2(u.y);           // (S, P)
                #pragma unroll
                for (int p = 0; p < 8; ++p) {
                    int tt = j - p;
                    if (tt >= 0 && tt < 11) {
                        float w = gw.g[tt];
                        v2f wv = (v2f){w, w};
                        res01[p] += wv * f01;     // pk_fma
                        res23[p] += wv * f23;     // pk_fma
                    }
                }
            }
            const float C1c = 0.0001f, C2c = 0.0009f;
            #pragma unroll
            for (int p = 0; p < 8; ++p) {
                float mu1 = res01[p].x, mu2 = res01[p].y;
                float S   = res23[p].x, P   = res23[p].y;
                float m11 = mu1 * mu1, m22 = mu2 * mu2, m12 = mu1 * mu2;
                float num = (2.f * m12 + C1c) * (2.f * (P - m12) + C2c);
                float den = (m11 + m22 + C1c) * ((S - m11 - m22) + C2c);
                float inv = __builtin_amdgcn_rcpf(den);  // ~1ulp vs 2.3e-2 thr
                local -= num * inv;
            }
        }

        if (t + 1 < NT) {
            __syncthreads();                      // phase-2 reads done; reuse hbuf
            const int nrow0 = row0 + TILE_H;
            float4 xB1[5], xB2[5];
            loadRow(nrow0 + 27 + rs, xB1, xB2);   // issue B
            convStore(rs, xP1, xP2);              // A compute (prefetched)
            if (third) loadRow(nrow0 + 59 + rs, xP1, xP2);   // issue C
            convStore(rs + 32, xB1, xB2);         // B compute under C latency
            if (third) convStore(rs + 64, xP1, xP2);
        }
    }

    // ---- block reduce ----
    #pragma unroll
    for (int off = 32; off > 0; off >>= 1) local += __shfl_down(local, off);
    if ((tid & 63) == 0) red[tid >> 6] = local;
    __syncthreads();
    if (tid == 0)
        partial[(plane * 2 + half) * CT + bx] =
            (red[0] + red[1]) + (red[2] + red[3]);
}

__global__ __launch_bounds__(256)
void ssim_finish(const float* __restrict__ partial, float* __restrict__ out)
{
    __shared__ float red[256];
    float s = 0.f;
    #pragma unroll
    for (int i = 0; i < NBLOCKS / 256; ++i)       // 6 independent loads
        s += partial[i * 256 + threadIdx.x];
    red[threadIdx.x] = s;
    __syncthreads();
    for (int step = 128; step > 0; step >>= 1) {
        if ((int)threadIdx.x < step) red[threadIdx.x] += red[threadIdx.x + step];
        __syncthreads();
    }
    if (threadIdx.x == 0)
        out[0] = 1.0f + red[0] * (1.0f / 12582912.0f);
}

extern "C" void kernel_launch(void* const* d_in, const int* in_sizes, int n_in,
                              void* d_out, int out_size, void* d_ws, size_t ws_size,
                              hipStream_t stream)
{
    const float* r_low  = (const float*)d_in[0];
    const float* r_high = (const float*)d_in[1];
    float* out     = (float*)d_out;
    float* partial = (float*)d_ws;                       // 1536 floats = 6 KB

    GW gw;                                               // gaussian -> SGPRs
    {
        float s = 0.f;
        for (int i = 0; i < 11; ++i) {
            float c = (float)(i - 5);
            gw.g[i] = expf(-(c * c) / 4.5f);             // 2*sigma^2 = 4.5
            s += gw.g[i];
        }
        for (int i = 0; i < 11; ++i) gw.g[i] /= s;
    }

    dim3 grid(CT, 2, NPLANES);
    ssim_main<<<grid, dim3(256), 0, stream>>>(r_low, r_high, partial, gw);
    ssim_finish<<<1, dim3(256), 0, stream>>>(partial, out);
}

// Round 10
// 147.676 us; speedup vs baseline: 1.0525x; 1.0197x over previous
//
#include <hip/hip_runtime.h>
#include <cmath>

// RestorationLoss = (1 - mean(SSIM(r_low, r_high))) + mean((r_low - r_high)^2)
// Separable 11x11 gaussian; 4 conv fields: mu1, mu2, S=conv(a^2+b^2), P=conv(ab).
// out = 1 + sum(d^2 - ssim_px)/N.
// R21 = R18 skeleton + MFMA vertical conv (idle-pipe round).
// R20 post-mortem: wall 65us = ~31us VALU issue + ~34us unhideable stalls;
// occupancy lever exhausted (R17-R20). MfmaUtil = 0% -- idle pipe. Vertical
// conv IS a banded matmul: D[m,n] = sum_k W[m,k] H[k,n], W[m,k]=g[k-m].
//  - correctness under ANY HW k-permutation: A/B both generated with the
//    SAME assumed mapping k~ = 8*(lane>>4)+j; sum over k is permutation-
//    invariant. Only C/D layout is relied on (m89 HW-verified:
//    col=lane&15, row=4*(lane>>4)+reg).
//  - hbufT[n=f*32+col][srow] fp16, pad 88 (16B-aligned rows, 8 start banks).
//    Phase-1 conv writes 16 ds_write_b16 per convStore (transposed).
//    srows 74..87 zeroed once (zero-weight tail must not be NaN).
//  - phase-2 per wave: out-block m0=16*wid; per (cb,f): 1 ds_read_b128
//    B-frag + 1 mfma_f32_16x16x32_f16 vs constant W-frag (built once from
//    gt[] LDS gaussian table); ssim epilogue on D regs (8 px/lane).
//  - fp16 staging precision validated (R15-R17/R20 all passed).
// Frozen: persistent 32-col strips (768 blocks = 3/CU), NT=8 chained tiles,
// depth-1 xP prefetch, packed-f32 (v2f) phase-1 conv, MSE folded in phase-1
// (rl in [5,69)), interior-col fast path, rcp ssim epilogue, 256 thr,
// launch_bounds(256,3), unroll-1 tile loop.

#define HH 512
#define WW 512
#define TILE_H 64
#define TILE_W 32
#define NT (HH / TILE_H)                          // 8 chained tiles per block
#define HB (TILE_H + 10)                          // 74 staged rows
#define TPAD 88                                   // hbufT row pad (halves)
#define NPLANES 48
#define CT (WW / TILE_W)                          // 16
#define NBLOCKS (NPLANES * CT)                    // 768 = 3 per CU exactly

struct GW { float g[11]; };

typedef float v2f __attribute__((ext_vector_type(2)));
typedef _Float16 f16x8 __attribute__((ext_vector_type(8)));
typedef float f32x4 __attribute__((ext_vector_type(4)));

__global__ __launch_bounds__(256, 3)
void ssim_main(const float* __restrict__ img1, const float* __restrict__ img2,
               float* __restrict__ partial, GW gw)
{
    __shared__ _Float16 hbufT[128][TPAD];         // [n=f*32+col][srow]: 22528 B
    __shared__ float red[4];
    __shared__ float gt[16];                      // gaussian table (gt[11..15]=0)

    const int tid   = threadIdx.x;
    const int bx    = blockIdx.x;                 // column strip
    const int plane = blockIdx.y;
    const int col0  = bx * TILE_W;
    const float* p1 = img1 + (size_t)plane * (HH * WW);
    const float* p2 = img2 + (size_t)plane * (HH * WW);

    const int cg    = tid & 7;                    // col group: tile cols 4cg..4cg+3
    const int rs    = tid >> 3;                   // 0..31 row slot
    const int cbase = col0 + 4 * cg - 8;          // 20-float window, 16B aligned
    const bool interiorCol = (bx > 0) && (bx < CT - 1);

    const int lane = tid & 63;
    const int l15  = lane & 15;
    const int lc   = lane >> 4;                   // k-group 0..3
    const int wv   = tid >> 6;                    // wave id 0..3 -> out-row block

    float local = 0.f;                            // mse (phase 1) - ssim (phase 2)

    // ---- one-time init: gaussian table, zero tail rows, W fragment ----
    if (tid < 16) gt[tid] = (tid < 11) ? gw.g[tid] : 0.f;
    if (tid < 128) {
        #pragma unroll
        for (int s = HB; s < TPAD; ++s) hbufT[tid][s] = (_Float16)0.f;
    }
    __syncthreads();
    f16x8 wfrag;                                  // A = W[m=l15][k~=8lc+j]=g[k-m]
    #pragma unroll
    for (int j = 0; j < 8; ++j) {
        int idx = 8 * lc + j - l15;
        int ridx = (idx >= 0 && idx <= 10) ? idx : 11;     // gt[11] == 0
        wfrag[j] = (_Float16)gt[ridx];
    }

    // 5 float4-pair loads; fast path for interior columns + in-bounds row.
    auto loadRow = [&](int grow, float4* x1, float4* x2) {
        const bool rowOK = (grow >= 0) && (grow < HH);
        const int growc = min(max(grow, 0), HH - 1);
        const float* r1 = p1 + (size_t)growc * WW;
        const float* r2 = p2 + (size_t)growc * WW;
        if (rowOK && interiorCol) {
            #pragma unroll
            for (int v = 0; v < 5; ++v) {
                x1[v] = *reinterpret_cast<const float4*>(r1 + cbase + 4 * v);
                x2[v] = *reinterpret_cast<const float4*>(r2 + cbase + 4 * v);
            }
        } else {
            #pragma unroll
            for (int v = 0; v < 5; ++v) {
                const int c0 = cbase + 4 * v;
                if (rowOK && c0 >= 0 && c0 + 4 <= WW) {
                    x1[v] = *reinterpret_cast<const float4*>(r1 + c0);
                    x2[v] = *reinterpret_cast<const float4*>(r2 + c0);
                } else {
                    x1[v] = make_float4(0.f, 0.f, 0.f, 0.f);
                    x2[v] = make_float4(0.f, 0.f, 0.f, 0.f);
                }
            }
        }
    };

    // horizontal conv of one staged row -> TRANSPOSED fp16 hbufT[n][rl]
    // + MSE for tile rows (rl in [5,68]).
    auto convStore = [&](int rl, const float4* x1v, const float4* x2v) {
        const float* x1 = reinterpret_cast<const float*>(x1v);
        const float* x2 = reinterpret_cast<const float*>(x2v);
        if (rl >= 5 && rl < 69) {
            #pragma unroll
            for (int i = 0; i < 4; ++i) {
                float d = x1[8 + i] - x2[8 + i];
                local += d * d;
            }
        }
        v2f acc01[4], acc23[4];
        #pragma unroll
        for (int i = 0; i < 4; ++i) {
            acc01[i] = (v2f){0.f, 0.f};
            acc23[i] = (v2f){0.f, 0.f};
        }
        #pragma unroll
        for (int e = 3; e <= 16; ++e) {           // out col i uses e = i+j+3
            float a  = x1[e], b = x2[e];
            v2f ab = (v2f){a, b};
            v2f t  = ab * ab;
            v2f vv = (v2f){t.x + t.y, a * b};
            #pragma unroll
            for (int i = 0; i < 4; ++i) {
                int j = e - 3 - i;
                if (j >= 0 && j < 11) {
                    float w = gw.g[j];
                    v2f wv2 = (v2f){w, w};
                    acc01[i] += wv2 * ab;
                    acc23[i] += wv2 * vv;
                }
            }
        }
        _Float16* hb = &hbufT[0][0] + (4 * cg) * TPAD + rl;
        #pragma unroll
        for (int i = 0; i < 4; ++i) {             // n = f*32 + (4cg+i)
            hb[i * TPAD + 0 * 32 * TPAD] = (_Float16)acc01[i].x;  // mu1
            hb[i * TPAD + 1 * 32 * TPAD] = (_Float16)acc01[i].y;  // mu2
            hb[i * TPAD + 2 * 32 * TPAD] = (_Float16)acc23[i].x;  // S
            hb[i * TPAD + 3 * 32 * TPAD] = (_Float16)acc23[i].y;  // P
        }
    };

    const bool third = (rs < 10);

    // ---- initial full staging of tile 0 (R9 pipeline) ----
    {
        float4 xA1[5], xA2[5], xB1[5], xB2[5];
        loadRow(-5 + rs, xA1, xA2);               // rows -5..26 (zero-fill OOB)
        loadRow(27 + rs, xB1, xB2);               // rows 27..58
        convStore(rs, xA1, xA2);
        if (third) loadRow(59 + rs, xA1, xA2);    // rows 59..68
        convStore(rs + 32, xB1, xB2);
        if (third) convStore(rs + 64, xA1, xA2);
    }

    float4 xP1[5], xP2[5];                        // next-tile batch-A prefetch
    #pragma unroll 1
    for (int t = 0; t < NT; ++t) {
        const int row0 = t * TILE_H;
        __syncthreads();                          // staging of tile t complete

        if (t + 1 < NT)                           // T14: issue next tile's A loads
            loadRow(row0 + TILE_H - 5 + rs, xP1, xP2);

        // ---- Phase 2: MFMA vertical conv + ssim ----
        // wave wv: out rows m0..m0+15; per (cb,f): D = W @ H-slab
        {
            const int m0 = wv * 16;
            const float C1c = 0.0001f, C2c = 0.0009f;
            #pragma unroll
            for (int cb = 0; cb < 2; ++cb) {
                f32x4 D[4];
                #pragma unroll
                for (int f = 0; f < 4; ++f) {
                    const _Float16* src =
                        &hbufT[f * 32 + cb * 16 + l15][m0 + 8 * lc];
                    f16x8 bfrag = *reinterpret_cast<const f16x8*>(src);
                    D[f] = __builtin_amdgcn_mfma_f32_16x16x32_f16(
                        wfrag, bfrag, (f32x4){0.f, 0.f, 0.f, 0.f}, 0, 0, 0);
                }
                #pragma unroll
                for (int r = 0; r < 4; ++r) {
                    float mu1 = D[0][r], mu2 = D[1][r];
                    float S   = D[2][r], P   = D[3][r];
                    float m11 = mu1 * mu1, m22 = mu2 * mu2, m12 = mu1 * mu2;
                    float num = (2.f * m12 + C1c) * (2.f * (P - m12) + C2c);
                    float den = (m11 + m22 + C1c) * ((S - m11 - m22) + C2c);
                    float inv = __builtin_amdgcn_rcpf(den);
                    local -= num * inv;
                }
            }
        }

        if (t + 1 < NT) {
            __syncthreads();                      // phase-2 reads done; reuse LDS
            const int nrow0 = row0 + TILE_H;
            float4 xB1[5], xB2[5];
            loadRow(nrow0 + 27 + rs, xB1, xB2);   // issue B
            convStore(rs, xP1, xP2);              // A compute (prefetched)
            if (third) loadRow(nrow0 + 59 + rs, xP1, xP2);   // issue C
            convStore(rs + 32, xB1, xB2);         // B compute under C latency
            if (third) convStore(rs + 64, xP1, xP2);
        }
    }

    // ---- block reduce ----
    #pragma unroll
    for (int off = 32; off > 0; off >>= 1) local += __shfl_down(local, off);
    if ((tid & 63) == 0) red[tid >> 6] = local;
    __syncthreads();
    if (tid == 0)
        partial[plane * CT + bx] = (red[0] + red[1]) + (red[2] + red[3]);
}

__global__ __launch_bounds__(256)
void ssim_finish(const float* __restrict__ partial, float* __restrict__ out)
{
    __shared__ float red[256];
    float s = 0.f;
    #pragma unroll
    for (int i = 0; i < NBLOCKS / 256; ++i)       // 3 independent loads
        s += partial[i * 256 + threadIdx.x];
    red[threadIdx.x] = s;
    __syncthreads();
    for (int step = 128; step > 0; step >>= 1) {
        if ((int)threadIdx.x < step) red[threadIdx.x] += red[threadIdx.x + step];
        __syncthreads();
    }
    if (threadIdx.x == 0)
        out[0] = 1.0f + red[0] * (1.0f / 12582912.0f);
}

extern "C" void kernel_launch(void* const* d_in, const int* in_sizes, int n_in,
                              void* d_out, int out_size, void* d_ws, size_t ws_size,
                              hipStream_t stream)
{
    const float* r_low  = (const float*)d_in[0];
    const float* r_high = (const float*)d_in[1];
    float* out     = (float*)d_out;
    float* partial = (float*)d_ws;                       // 768 floats

    GW gw;                                               // gaussian -> SGPRs
    {
        float s = 0.f;
        for (int i = 0; i < 11; ++i) {
            float c = (float)(i - 5);
            gw.g[i] = expf(-(c * c) / 4.5f);             // 2*sigma^2 = 4.5
            s += gw.g[i];
        }
        for (int i = 0; i < 11; ++i) gw.g[i] /= s;
    }

    dim3 grid(CT, NPLANES);
    ssim_main<<<grid, dim3(256), 0, stream>>>(r_low, r_high, partial, gw);
    ssim_finish<<<1, dim3(256), 0, stream>>>(partial, out);
}